// Round 2
// baseline (1015.982 us; speedup 1.0000x reference)
//
#include <hip/hip_runtime.h>
#include <hip/hip_bf16.h>
#include <math.h>

#define INF 3.0e38f
#define KTILE 1024

// ---------------------------------------------------------------- 3-NN ----
// v2: 512 blocks x 256 threads. Block = 128 unknown points. The 4 waves each
// scan the j%4==s quarter of the knowns (wave-uniform LDS broadcast reads).
// Each lane owns 2 points so one ds_read_b128 feeds 2 distance evals.
// Partial top-3s merged via LDS with lexicographic (d, idx) tie-breaking to
// exactly match lax.top_k's lower-index-wins semantics.
// Outputs normalized inverse-distance weights + global indices.
__global__ __launch_bounds__(256) void knn3_kernel(
    const float* __restrict__ unk, const float* __restrict__ kn,
    const int* __restrict__ ucnt, const int* __restrict__ kcnt,
    int B, int N, float* __restrict__ wgt, int* __restrict__ idxo)
{
    __shared__ float4 kxyz[KTILE];
    __shared__ float4 candd[4][128];
    __shared__ int4   candi[4][128];

    int tid = threadIdx.x;
    int s = tid >> 6;          // wave id 0..3
    int lane = tid & 63;
    int pbase = blockIdx.x * 128;
    int pA = pbase + lane, pB = pA + 64;

    // batch of this block (batch counts are multiples of 128 -> block-uniform)
    int cum = 0, bb = 0;
    for (int i = 0; i < B; i++) { int c = ucnt[i]; if (pbase >= cum) bb = i; cum += c; }
    int kstart = 0;
    for (int i = 0; i < bb; i++) kstart += kcnt[i];
    int kend = kstart + kcnt[bb];

    float uxA = unk[pA * 3 + 0], uyA = unk[pA * 3 + 1], uzA = unk[pA * 3 + 2];
    float uxB = unk[pB * 3 + 0], uyB = unk[pB * 3 + 1], uzB = unk[pB * 3 + 2];

    float dA0 = INF, dA1 = INF, dA2 = INF, dB0 = INF, dB1 = INF, dB2 = INF;
    int   iA0 = 0, iA1 = 0, iA2 = 0, iB0 = 0, iB1 = 0, iB2 = 0;

    // strict-< insert: on ties keeps incumbent (lower j, since scan ascending)
    auto ins = [](float d, int gi, float& d0, float& d1, float& d2,
                  int& i0, int& i1, int& i2) {
        if (d < d2) {
            if (d < d1) {
                d2 = d1; i2 = i1;
                if (d < d0) { d1 = d0; i1 = i0; d0 = d; i0 = gi; }
                else        { d1 = d;  i1 = gi; }
            } else { d2 = d; i2 = gi; }
        }
    };

    for (int t0 = kstart; t0 < kend; t0 += KTILE) {
        int cnt = min(KTILE, kend - t0);
        __syncthreads();
        for (int f = tid; f < cnt * 3; f += 256) {
            int pt = f / 3, comp = f - pt * 3;
            ((float*)&kxyz[pt])[comp] = kn[(size_t)(t0 + pt) * 3 + comp];
        }
        __syncthreads();

        int jj = s;
        for (; jj + 12 < cnt; jj += 16) {
            float4 k0 = kxyz[jj];
            float4 k1 = kxyz[jj + 4];
            float4 k2 = kxyz[jj + 8];
            float4 k3 = kxyz[jj + 12];

            float ax0 = uxA - k0.x, ay0 = uyA - k0.y, az0 = uzA - k0.z;
            float ax1 = uxA - k1.x, ay1 = uyA - k1.y, az1 = uzA - k1.z;
            float ax2 = uxA - k2.x, ay2 = uyA - k2.y, az2 = uzA - k2.z;
            float ax3 = uxA - k3.x, ay3 = uyA - k3.y, az3 = uzA - k3.z;
            float eA0 = ax0 * ax0 + ay0 * ay0 + az0 * az0;
            float eA1 = ax1 * ax1 + ay1 * ay1 + az1 * az1;
            float eA2 = ax2 * ax2 + ay2 * ay2 + az2 * az2;
            float eA3 = ax3 * ax3 + ay3 * ay3 + az3 * az3;

            float bx0 = uxB - k0.x, by0 = uyB - k0.y, bz0 = uzB - k0.z;
            float bx1 = uxB - k1.x, by1 = uyB - k1.y, bz1 = uzB - k1.z;
            float bx2 = uxB - k2.x, by2 = uyB - k2.y, bz2 = uzB - k2.z;
            float bx3 = uxB - k3.x, by3 = uyB - k3.y, bz3 = uzB - k3.z;
            float eB0 = bx0 * bx0 + by0 * by0 + bz0 * bz0;
            float eB1 = bx1 * bx1 + by1 * by1 + bz1 * bz1;
            float eB2 = bx2 * bx2 + by2 * by2 + bz2 * bz2;
            float eB3 = bx3 * bx3 + by3 * by3 + bz3 * bz3;

            float mA = fminf(fminf(eA0, eA1), fminf(eA2, eA3));
            if (mA < dA2) {
                ins(eA0, t0 + jj,      dA0, dA1, dA2, iA0, iA1, iA2);
                ins(eA1, t0 + jj + 4,  dA0, dA1, dA2, iA0, iA1, iA2);
                ins(eA2, t0 + jj + 8,  dA0, dA1, dA2, iA0, iA1, iA2);
                ins(eA3, t0 + jj + 12, dA0, dA1, dA2, iA0, iA1, iA2);
            }
            float mB = fminf(fminf(eB0, eB1), fminf(eB2, eB3));
            if (mB < dB2) {
                ins(eB0, t0 + jj,      dB0, dB1, dB2, iB0, iB1, iB2);
                ins(eB1, t0 + jj + 4,  dB0, dB1, dB2, iB0, iB1, iB2);
                ins(eB2, t0 + jj + 8,  dB0, dB1, dB2, iB0, iB1, iB2);
                ins(eB3, t0 + jj + 12, dB0, dB1, dB2, iB0, iB1, iB2);
            }
        }
        for (; jj < cnt; jj += 4) {          // generic tail (unused when cnt=1024)
            float4 k0 = kxyz[jj];
            float ax = uxA - k0.x, ay = uyA - k0.y, az = uzA - k0.z;
            float eA = ax * ax + ay * ay + az * az;
            ins(eA, t0 + jj, dA0, dA1, dA2, iA0, iA1, iA2);
            float bx = uxB - k0.x, by = uyB - k0.y, bz = uzB - k0.z;
            float eB = bx * bx + by * by + bz * bz;
            ins(eB, t0 + jj, dB0, dB1, dB2, iB0, iB1, iB2);
        }
    }

    candd[s][lane]      = { dA0, dA1, dA2, 0.0f };
    candi[s][lane]      = { iA0, iA1, iA2, 0 };
    candd[s][lane + 64] = { dB0, dB1, dB2, 0.0f };
    candi[s][lane + 64] = { iB0, iB1, iB2, 0 };
    __syncthreads();

    if (tid < 128) {
        float bd0 = INF, bd1 = INF, bd2 = INF;
        int   bi0 = 0, bi1 = 0, bi2 = 0;
        // lexicographic (d, idx) insert: reproduces global ascending-j scan order
        auto insL = [&](float d, int gi) {
            if (d < bd2 || (d == bd2 && gi < bi2)) {
                if (d < bd1 || (d == bd1 && gi < bi1)) {
                    bd2 = bd1; bi2 = bi1;
                    if (d < bd0 || (d == bd0 && gi < bi0)) {
                        bd1 = bd0; bi1 = bi0; bd0 = d; bi0 = gi;
                    } else { bd1 = d; bi1 = gi; }
                } else { bd2 = d; bi2 = gi; }
            }
        };
#pragma unroll
        for (int w = 0; w < 4; w++) {
            float4 dd = candd[w][tid];
            int4   ii = candi[w][tid];
            insL(dd.x, ii.x);
            insL(dd.y, ii.y);
            insL(dd.z, ii.z);
        }
        float r0 = 1.0f / (bd0 + 1e-8f);
        float r1 = 1.0f / (bd1 + 1e-8f);
        float r2 = 1.0f / (bd2 + 1e-8f);
        float rs = 1.0f / (r0 + r1 + r2);
        int p = pbase + tid;
        wgt[p * 3 + 0] = r0 * rs;
        wgt[p * 3 + 1] = r1 * rs;
        wgt[p * 3 + 2] = r2 * rs;
        idxo[p * 3 + 0] = bi0;
        idxo[p * 3 + 1] = bi1;
        idxo[p * 3 + 2] = bi2;
    }
}

// -------------------------------------------------- interpolate (C2=256) --
// 64 lanes cover one point's 256 channels (float4 each); 4 points per block.
__global__ __launch_bounds__(256) void interp_kernel(
    const float* __restrict__ wv, const int* __restrict__ idxv,
    const float* __restrict__ kf, float* __restrict__ outv, int N)
{
    int t = blockIdx.x * 256 + threadIdx.x;
    int p = t >> 6;
    int c4 = t & 63;
    if (p >= N) return;

    float w0 = wv[p * 3 + 0], w1 = wv[p * 3 + 1], w2 = wv[p * 3 + 2];
    int j0 = idxv[p * 3 + 0], j1 = idxv[p * 3 + 1], j2 = idxv[p * 3 + 2];
    float4 v0 = ((const float4*)(kf + (size_t)j0 * 256))[c4];
    float4 v1 = ((const float4*)(kf + (size_t)j1 * 256))[c4];
    float4 v2 = ((const float4*)(kf + (size_t)j2 * 256))[c4];

    float4 o;
    o.x = v0.x * w0 + v1.x * w1 + v2.x * w2;
    o.y = v0.y * w0 + v1.y * w1 + v2.y * w2;
    o.z = v0.z * w0 + v1.z * w1 + v2.z * w2;
    o.w = v0.w * w0 + v1.w * w1 + v2.w * w2;
    ((float4*)(outv + (size_t)p * 256))[c4] = o;
}

// -------------------------------------------------------------- fp32 GEMM --
// C[N,256] = A[N,K] * W^T, W is [Cout,K] row-major.
// MODE 0: A = [interp | unknown_feats] (K=384, split at k=256)
// MODE 1: A = relu(h1*scale + shift) read from A0 (K=256)
#define BM 128
#define BN 128
#define BK 16

template <int MODE>
__global__ __launch_bounds__(256) void gemm_kernel(
    const float* __restrict__ A0, const float* __restrict__ A1,
    const float* __restrict__ Bw,
    const float* __restrict__ scale, const float* __restrict__ shift,
    float* __restrict__ C, int N, int K, int Cout)
{
    __shared__ float As[BK][BM + 4];
    __shared__ float Bs[BK][BN + 4];

    int tid = threadIdx.x;
    int ty = tid >> 4;          // 0..15  (row group)
    int tx = tid & 15;          // 0..15  (col group)
    int bm = blockIdx.x * BM;
    int bn = blockIdx.y * BN;

    float acc[8][8];
#pragma unroll
    for (int i = 0; i < 8; i++)
#pragma unroll
        for (int j = 0; j < 8; j++) acc[i][j] = 0.0f;

    int nkb = K / BK;
    for (int kb = 0; kb < nkb; kb++) {
        int k0 = kb * BK;
        // stage A: 128x16 floats = 512 float4, 2 per thread
#pragma unroll
        for (int i = 0; i < 2; i++) {
            int id = tid + i * 256;
            int row = id >> 2;
            int kq = (id & 3) * 4;
            int gk = k0 + kq;
            int gr = bm + row;
            float4 v;
            if (MODE == 0) {
                if (gk < 256) v = *(const float4*)(A0 + (size_t)gr * 256 + gk);
                else          v = *(const float4*)(A1 + (size_t)gr * 128 + (gk - 256));
            } else {
                v = *(const float4*)(A0 + (size_t)gr * 256 + gk);
                float4 s4 = *(const float4*)(scale + gk);
                float4 t4 = *(const float4*)(shift + gk);
                v.x = fmaxf(v.x * s4.x + t4.x, 0.0f);
                v.y = fmaxf(v.y * s4.y + t4.y, 0.0f);
                v.z = fmaxf(v.z * s4.z + t4.z, 0.0f);
                v.w = fmaxf(v.w * s4.w + t4.w, 0.0f);
            }
            As[kq + 0][row] = v.x;
            As[kq + 1][row] = v.y;
            As[kq + 2][row] = v.z;
            As[kq + 3][row] = v.w;
        }
        // stage B: Bs[k][n] = Bw[(bn+n)*K + k0 + k]
#pragma unroll
        for (int i = 0; i < 2; i++) {
            int id = tid + i * 256;
            int col = id >> 2;
            int kq = (id & 3) * 4;
            float4 v = *(const float4*)(Bw + (size_t)(bn + col) * K + k0 + kq);
            Bs[kq + 0][col] = v.x;
            Bs[kq + 1][col] = v.y;
            Bs[kq + 2][col] = v.z;
            Bs[kq + 3][col] = v.w;
        }
        __syncthreads();

#pragma unroll
        for (int k = 0; k < BK; k++) {
            float a[8], b[8];
            *(float4*)&a[0] = *(const float4*)&As[k][ty * 8];
            *(float4*)&a[4] = *(const float4*)&As[k][ty * 8 + 4];
            *(float4*)&b[0] = *(const float4*)&Bs[k][tx * 8];
            *(float4*)&b[4] = *(const float4*)&Bs[k][tx * 8 + 4];
#pragma unroll
            for (int i = 0; i < 8; i++)
#pragma unroll
                for (int j = 0; j < 8; j++)
                    acc[i][j] += a[i] * b[j];
        }
        __syncthreads();
    }

    // store C (row stride Cout)
#pragma unroll
    for (int i = 0; i < 8; i++) {
        int gr = bm + ty * 8 + i;
        float* cp = C + (size_t)gr * Cout + bn + tx * 8;
        float4 v0 = { acc[i][0], acc[i][1], acc[i][2], acc[i][3] };
        float4 v1 = { acc[i][4], acc[i][5], acc[i][6], acc[i][7] };
        *(float4*)(cp + 0) = v0;
        *(float4*)(cp + 4) = v1;
    }
}

// ----------------------------------------------------------- BN statistics --
__global__ __launch_bounds__(256) void bn_stats_kernel(
    const float* __restrict__ h, int N, float* __restrict__ sum,
    float* __restrict__ sumsq)
{
    int c4 = threadIdx.x & 63;     // float4 column group (4 channels)
    int rl = threadIdx.x >> 6;     // 0..3
    float4 s = {0, 0, 0, 0}, q = {0, 0, 0, 0};
    for (int r = blockIdx.x * 4 + rl; r < N; r += gridDim.x * 4) {
        float4 v = ((const float4*)(h + (size_t)r * 256))[c4];
        s.x += v.x; s.y += v.y; s.z += v.z; s.w += v.w;
        q.x += v.x * v.x; q.y += v.y * v.y; q.z += v.z * v.z; q.w += v.w * v.w;
    }
    __shared__ float4 ls[4][64];
    __shared__ float4 lq[4][64];
    ls[rl][c4] = s;
    lq[rl][c4] = q;
    __syncthreads();
    if (threadIdx.x < 64) {
        float4 S = {0, 0, 0, 0}, Q = {0, 0, 0, 0};
#pragma unroll
        for (int i = 0; i < 4; i++) {
            S.x += ls[i][c4].x; S.y += ls[i][c4].y; S.z += ls[i][c4].z; S.w += ls[i][c4].w;
            Q.x += lq[i][c4].x; Q.y += lq[i][c4].y; Q.z += lq[i][c4].z; Q.w += lq[i][c4].w;
        }
        atomicAdd(&sum[c4 * 4 + 0], S.x);
        atomicAdd(&sum[c4 * 4 + 1], S.y);
        atomicAdd(&sum[c4 * 4 + 2], S.z);
        atomicAdd(&sum[c4 * 4 + 3], S.w);
        atomicAdd(&sumsq[c4 * 4 + 0], Q.x);
        atomicAdd(&sumsq[c4 * 4 + 1], Q.y);
        atomicAdd(&sumsq[c4 * 4 + 2], Q.z);
        atomicAdd(&sumsq[c4 * 4 + 3], Q.w);
    }
}

__global__ void bn_finalize_kernel(
    const float* __restrict__ sum, const float* __restrict__ sumsq,
    const float* __restrict__ g, const float* __restrict__ bta, float invN,
    float* __restrict__ scale, float* __restrict__ shift)
{
    int c = threadIdx.x;   // 256 channels
    float mean = sum[c] * invN;
    float var = sumsq[c] * invN - mean * mean;   // biased, matches torch BN
    float sc = g[c] * rsqrtf(var + 1e-5f);
    scale[c] = sc;
    shift[c] = bta[c] - mean * sc;
}

// --------------------------------------------------------- final activation --
__global__ __launch_bounds__(256) void final_act_kernel(
    const float* __restrict__ h2, const float* __restrict__ scale,
    const float* __restrict__ shift, float* __restrict__ out, int total4)
{
    int i = blockIdx.x * 256 + threadIdx.x;
    if (i >= total4) return;
    int c4 = i & 63;
    float4 v = ((const float4*)h2)[i];
    float4 s = ((const float4*)scale)[c4];
    float4 t = ((const float4*)shift)[c4];
    float4 o;
    o.x = fmaxf(v.x * s.x + t.x, 0.0f);
    o.y = fmaxf(v.y * s.y + t.y, 0.0f);
    o.z = fmaxf(v.z * s.z + t.z, 0.0f);
    o.w = fmaxf(v.w * s.w + t.w, 0.0f);
    ((float4*)out)[i] = o;
}

// ------------------------------------------------------------------ launch --
extern "C" void kernel_launch(void* const* d_in, const int* in_sizes, int n_in,
                              void* d_out, int out_size, void* d_ws, size_t ws_size,
                              hipStream_t stream)
{
    const float* unknown = (const float*)d_in[0];
    const int*   ucnt    = (const int*)d_in[1];
    const float* known   = (const float*)d_in[2];
    const int*   kcnt    = (const int*)d_in[3];
    const float* ufeat   = (const float*)d_in[4];
    const float* kfeat   = (const float*)d_in[5];
    const float* W1      = (const float*)d_in[6];
    const float* g1      = (const float*)d_in[7];
    const float* b1      = (const float*)d_in[8];
    const float* W2      = (const float*)d_in[9];
    const float* g2      = (const float*)d_in[10];
    const float* b2      = (const float*)d_in[11];

    int N = in_sizes[0] / 3;        // 65536
    int B = in_sizes[1];            // 4

    char* ws = (char*)d_ws;
    float* wgt   = (float*)ws;                       // N*3 floats
    int*   idxb  = (int*)(ws + (size_t)N * 3 * 4);   // N*3 ints
    float* stats = (float*)(ws + (size_t)N * 3 * 8); // 8*256 floats
    float* sum1 = stats,        *sq1 = stats + 256;
    float* scale1 = stats + 512, *shift1 = stats + 768;
    float* sum2 = stats + 1024, *sq2 = stats + 1280;
    float* scale2 = stats + 1536, *shift2 = stats + 1792;
    size_t big_off = ((size_t)N * 3 * 8 + 8 * 256 * 4 + 255) & ~(size_t)255;
    float* interp = (float*)(ws + big_off);          // N*256 floats; reused as h2
    float* h2 = interp;
    float* h1 = (float*)d_out;                       // h1 lives in d_out

    hipMemsetAsync(stats, 0, 8 * 256 * 4, stream);

    knn3_kernel<<<N / 128, 256, 0, stream>>>(unknown, known, ucnt, kcnt,
                                             B, N, wgt, idxb);
    interp_kernel<<<(N * 64 + 255) / 256, 256, 0, stream>>>(wgt, idxb, kfeat,
                                                            interp, N);
    gemm_kernel<0><<<dim3(N / BM, 256 / BN), 256, 0, stream>>>(
        interp, ufeat, W1, nullptr, nullptr, h1, N, 384, 256);
    bn_stats_kernel<<<512, 256, 0, stream>>>(h1, N, sum1, sq1);
    bn_finalize_kernel<<<1, 256, 0, stream>>>(sum1, sq1, g1, b1, 1.0f / N,
                                              scale1, shift1);
    gemm_kernel<1><<<dim3(N / BM, 256 / BN), 256, 0, stream>>>(
        h1, nullptr, W2, scale1, shift1, h2, N, 256, 256);
    bn_stats_kernel<<<512, 256, 0, stream>>>(h2, N, sum2, sq2);
    bn_finalize_kernel<<<1, 256, 0, stream>>>(sum2, sq2, g2, b2, 1.0f / N,
                                              scale2, shift2);
    final_act_kernel<<<(N * 64 + 255) / 256, 256, 0, stream>>>(
        h2, scale2, shift2, (float*)d_out, N * 64);
}

// Round 3
// 535.299 us; speedup vs baseline: 1.8980x; 1.8980x over previous
//
#include <hip/hip_runtime.h>
#include <math.h>

typedef __attribute__((ext_vector_type(8))) short short8;
typedef __attribute__((ext_vector_type(4))) float f32x4;

__device__ __forceinline__ unsigned short f2bf(float x) {
    union { float f; unsigned u; } v; v.f = x;
    unsigned r = v.u + 0x7FFF + ((v.u >> 16) & 1);   // RNE
    return (unsigned short)(r >> 16);
}

// ---------------------------------------------------------------- 3-NN ----
// Branch-free top-3 via u64 lex keys: key = (f32bits(d2)<<32) | idx.
// d2>=0 so f32 bits are order-preserving; u64 < == (d,idx) lex order ==
// lax.top_k semantics at FULL precision (no truncation, no tie hazard).
// 1024 blocks x 256 thr; block = 64 points, 4 threads/point scan quarter
// ranges of the LDS-staged knowns (wave-uniform broadcast reads).
__global__ __launch_bounds__(256) void knn3_kernel(
    const float* __restrict__ unk, const float* __restrict__ kn,
    const int* __restrict__ ucnt, const int* __restrict__ kcnt,
    int B, int N, float* __restrict__ wgt, int* __restrict__ idxo)
{
    __shared__ float4 kxyz[1024];
    __shared__ unsigned long long mk[4][64][3];

    int tid = threadIdx.x;
    int s = tid >> 6;
    int lane = tid & 63;
    int pbase = blockIdx.x * 64;
    int p = pbase + lane;

    int cum = 0, bb = 0;
    for (int i = 0; i < B; i++) { int c = ucnt[i]; if (pbase >= cum) bb = i; cum += c; }
    int kstart = 0;
    for (int i = 0; i < bb; i++) kstart += kcnt[i];
    int kend = kstart + kcnt[bb];

    float ux = unk[p * 3 + 0], uy = unk[p * 3 + 1], uz = unk[p * 3 + 2];

    unsigned long long s0 = ~0ULL, s1 = ~0ULL, s2 = ~0ULL;

    // branch-free sorted insert: 3 u64 cmps + 10 cndmasks
    auto ins = [&](unsigned long long k) {
        bool c0 = k < s0;
        unsigned long long t0 = c0 ? k : s0;
        unsigned long long t1 = c0 ? s0 : k;
        bool c1 = t1 < s1;
        unsigned long long u0 = c1 ? t1 : s1;
        unsigned long long u1 = c1 ? s1 : t1;
        s0 = t0; s1 = u0;
        s2 = u1 < s2 ? u1 : s2;
    };

    for (int t0g = kstart; t0g < kend; t0g += 1024) {
        int cnt = min(1024, kend - t0g);
        __syncthreads();
        for (int f = tid; f < cnt * 3; f += 256) {
            int pt = f / 3, c = f - pt * 3;
            ((float*)&kxyz[pt])[c] = kn[(size_t)(t0g + pt) * 3 + c];
        }
        __syncthreads();

        int qlen = cnt >> 2;          // cnt divisible by 4 (4096-per-batch)
        int base = s * qlen;
        for (int i = 0; i < qlen; i += 4) {
            float4 a = kxyz[base + i];
            float4 b4 = kxyz[base + i + 1];
            float4 c4 = kxyz[base + i + 2];
            float4 d4 = kxyz[base + i + 3];
            float ax = ux - a.x,  ay = uy - a.y,  az = uz - a.z;
            float bx = ux - b4.x, by = uy - b4.y, bz = uz - b4.z;
            float cx = ux - c4.x, cy = uy - c4.y, cz = uz - c4.z;
            float dx = ux - d4.x, dy = uy - d4.y, dz = uz - d4.z;
            float e0 = ax * ax + ay * ay + az * az;
            float e1 = bx * bx + by * by + bz * bz;
            float e2 = cx * cx + cy * cy + cz * cz;
            float e3 = dx * dx + dy * dy + dz * dz;
            int gj = t0g + base + i;
            ins(((unsigned long long)__float_as_uint(e0) << 32) | (unsigned)(gj + 0));
            ins(((unsigned long long)__float_as_uint(e1) << 32) | (unsigned)(gj + 1));
            ins(((unsigned long long)__float_as_uint(e2) << 32) | (unsigned)(gj + 2));
            ins(((unsigned long long)__float_as_uint(e3) << 32) | (unsigned)(gj + 3));
        }
    }

    mk[s][lane][0] = s0;
    mk[s][lane][1] = s1;
    mk[s][lane][2] = s2;
    __syncthreads();

    if (tid < 64) {
        s0 = s1 = s2 = ~0ULL;
#pragma unroll
        for (int qq = 0; qq < 4; qq++) {
            ins(mk[qq][tid][0]);
            ins(mk[qq][tid][1]);
            ins(mk[qq][tid][2]);
        }
        float d0 = __uint_as_float((unsigned)(s0 >> 32));
        float d1 = __uint_as_float((unsigned)(s1 >> 32));
        float d2 = __uint_as_float((unsigned)(s2 >> 32));
        float r0 = 1.0f / (d0 + 1e-8f);
        float r1 = 1.0f / (d1 + 1e-8f);
        float r2 = 1.0f / (d2 + 1e-8f);
        float rs = 1.0f / (r0 + r1 + r2);
        int pp = pbase + tid;
        wgt[pp * 3 + 0] = r0 * rs;
        wgt[pp * 3 + 1] = r1 * rs;
        wgt[pp * 3 + 2] = r2 * rs;
        idxo[pp * 3 + 0] = (int)(unsigned)s0;
        idxo[pp * 3 + 1] = (int)(unsigned)s1;
        idxo[pp * 3 + 2] = (int)(unsigned)s2;
    }
}

// --------------------------- build A1 = [interp | ufeat] as bf16 [N,384] --
__global__ __launch_bounds__(256) void build_a1_kernel(
    const float* __restrict__ wgt, const int* __restrict__ idxv,
    const float* __restrict__ kfeat, const float* __restrict__ ufeat,
    unsigned short* __restrict__ A1, int N)
{
    int t = blockIdx.x * 256 + threadIdx.x;
    int p = t >> 6, c4 = t & 63;
    if (p >= N) return;
    float w0 = wgt[p * 3 + 0], w1 = wgt[p * 3 + 1], w2 = wgt[p * 3 + 2];
    int j0 = idxv[p * 3 + 0], j1 = idxv[p * 3 + 1], j2 = idxv[p * 3 + 2];
    float4 v0 = ((const float4*)(kfeat + (size_t)j0 * 256))[c4];
    float4 v1 = ((const float4*)(kfeat + (size_t)j1 * 256))[c4];
    float4 v2 = ((const float4*)(kfeat + (size_t)j2 * 256))[c4];
    ushort4 ob;
    ob.x = f2bf(v0.x * w0 + v1.x * w1 + v2.x * w2);
    ob.y = f2bf(v0.y * w0 + v1.y * w1 + v2.y * w2);
    ob.z = f2bf(v0.z * w0 + v1.z * w1 + v2.z * w2);
    ob.w = f2bf(v0.w * w0 + v1.w * w1 + v2.w * w2);
    *(ushort4*)(A1 + (size_t)p * 384 + c4 * 4) = ob;
    float2 u = ((const float2*)(ufeat + (size_t)p * 128))[c4];
    ushort2 ub; ub.x = f2bf(u.x); ub.y = f2bf(u.y);
    *(ushort2*)(A1 + (size_t)p * 384 + 256 + c4 * 2) = ub;
}

// ------------------------------------------------ weight fp32->bf16 conv --
__global__ __launch_bounds__(256) void wconv_kernel(
    const float* __restrict__ W1, const float* __restrict__ W2,
    unsigned short* __restrict__ W1b, unsigned short* __restrict__ W2b,
    int n1, int n2)
{
    int i = blockIdx.x * 256 + threadIdx.x;
    if (i < n1) W1b[i] = f2bf(W1[i]);
    int j = i - n1;
    if (j >= 0 && j < n2) W2b[j] = f2bf(W2[j]);
}

// -------------------------------------------------------- bf16 MFMA GEMM --
// C[N,256] = A[N,K](bf16) x W[256,K](bf16)^T.  128x128 tile, BK=32,
// 16x16x32 MFMA, LDS rows padded to 40 halfs (2-way-free banks).
template <int K>
__global__ __launch_bounds__(256) void gemm_bf16_kernel(
    const unsigned short* __restrict__ A, const unsigned short* __restrict__ W,
    float* __restrict__ C)
{
    __shared__ unsigned short As[128 * 40];
    __shared__ unsigned short Bs[128 * 40];

    int tid = threadIdx.x;
    int w = tid >> 6, lane = tid & 63;
    int r = w >> 1, cq = w & 1;
    int m16 = lane & 15, q = lane >> 4;
    int bm = blockIdx.x * 128, bn = blockIdx.y * 128;

    f32x4 acc[4][4];
#pragma unroll
    for (int i = 0; i < 4; i++)
#pragma unroll
        for (int j = 0; j < 4; j++) acc[i][j] = (f32x4){0.f, 0.f, 0.f, 0.f};

#pragma unroll
    for (int k0 = 0; k0 < K; k0 += 32) {
        __syncthreads();
#pragma unroll
        for (int i = 0; i < 2; i++) {
            int id = tid + i * 256;
            int row = id >> 2, kc = (id & 3) * 8;
            *(short8*)&As[row * 40 + kc] =
                *(const short8*)(A + (size_t)(bm + row) * K + k0 + kc);
            *(short8*)&Bs[row * 40 + kc] =
                *(const short8*)(W + (size_t)(bn + row) * K + k0 + kc);
        }
        __syncthreads();

        short8 af[4], bf[4];
#pragma unroll
        for (int sub = 0; sub < 4; sub++) {
            af[sub] = *(const short8*)&As[(r * 64 + sub * 16 + m16) * 40 + q * 8];
            bf[sub] = *(const short8*)&Bs[(cq * 64 + sub * 16 + m16) * 40 + q * 8];
        }
#pragma unroll
        for (int sm = 0; sm < 4; sm++)
#pragma unroll
            for (int sn = 0; sn < 4; sn++)
                acc[sm][sn] = __builtin_amdgcn_mfma_f32_16x16x32_bf16(
                    af[sm], bf[sn], acc[sm][sn], 0, 0, 0);
    }

    int row0 = bm + r * 64 + q * 4;
    int col0 = bn + cq * 64 + m16;
#pragma unroll
    for (int sm = 0; sm < 4; sm++)
#pragma unroll
        for (int sn = 0; sn < 4; sn++) {
            f32x4 v = acc[sm][sn];
#pragma unroll
            for (int reg = 0; reg < 4; reg++)
                C[(size_t)(row0 + sm * 16 + reg) * 256 + col0 + sn * 16] = v[reg];
        }
}

// ----------------------------------------------------------- BN statistics --
__global__ __launch_bounds__(256) void bn_stats_kernel(
    const float* __restrict__ h, int N, float* __restrict__ sum,
    float* __restrict__ sumsq)
{
    int c4 = threadIdx.x & 63;
    int rl = threadIdx.x >> 6;
    float4 s = {0, 0, 0, 0}, q = {0, 0, 0, 0};
    for (int r = blockIdx.x * 4 + rl; r < N; r += gridDim.x * 4) {
        float4 v = ((const float4*)(h + (size_t)r * 256))[c4];
        s.x += v.x; s.y += v.y; s.z += v.z; s.w += v.w;
        q.x += v.x * v.x; q.y += v.y * v.y; q.z += v.z * v.z; q.w += v.w * v.w;
    }
    __shared__ float4 ls[4][64];
    __shared__ float4 lq[4][64];
    ls[rl][c4] = s;
    lq[rl][c4] = q;
    __syncthreads();
    if (threadIdx.x < 64) {
        float4 S = {0, 0, 0, 0}, Q = {0, 0, 0, 0};
#pragma unroll
        for (int i = 0; i < 4; i++) {
            S.x += ls[i][c4].x; S.y += ls[i][c4].y; S.z += ls[i][c4].z; S.w += ls[i][c4].w;
            Q.x += lq[i][c4].x; Q.y += lq[i][c4].y; Q.z += lq[i][c4].z; Q.w += lq[i][c4].w;
        }
        atomicAdd(&sum[c4 * 4 + 0], S.x);
        atomicAdd(&sum[c4 * 4 + 1], S.y);
        atomicAdd(&sum[c4 * 4 + 2], S.z);
        atomicAdd(&sum[c4 * 4 + 3], S.w);
        atomicAdd(&sumsq[c4 * 4 + 0], Q.x);
        atomicAdd(&sumsq[c4 * 4 + 1], Q.y);
        atomicAdd(&sumsq[c4 * 4 + 2], Q.z);
        atomicAdd(&sumsq[c4 * 4 + 3], Q.w);
    }
}

__global__ void bn_finalize_kernel(
    const float* __restrict__ sum, const float* __restrict__ sumsq,
    const float* __restrict__ g, const float* __restrict__ bta, float invN,
    float* __restrict__ scale, float* __restrict__ shift)
{
    int c = threadIdx.x;
    float mean = sum[c] * invN;
    float var = sumsq[c] * invN - mean * mean;   // biased, matches torch BN
    float sc = g[c] * rsqrtf(var + 1e-5f);
    scale[c] = sc;
    shift[c] = bta[c] - mean * sc;
}

// ---------------------- act1: h1(fp32) -> relu(bn) -> A2 (bf16 [N,256]) --
__global__ __launch_bounds__(256) void act1_kernel(
    const float* __restrict__ h1, const float* __restrict__ scale,
    const float* __restrict__ shift, unsigned short* __restrict__ A2, int N)
{
    int t = blockIdx.x * 256 + threadIdx.x;
    int p = t >> 6, c4 = t & 63;
    if (p >= N) return;
    float4 v = ((const float4*)(h1 + (size_t)p * 256))[c4];
    float4 s = ((const float4*)scale)[c4];
    float4 b = ((const float4*)shift)[c4];
    ushort4 o;
    o.x = f2bf(fmaxf(v.x * s.x + b.x, 0.0f));
    o.y = f2bf(fmaxf(v.y * s.y + b.y, 0.0f));
    o.z = f2bf(fmaxf(v.z * s.z + b.z, 0.0f));
    o.w = f2bf(fmaxf(v.w * s.w + b.w, 0.0f));
    *(ushort4*)(A2 + (size_t)p * 256 + c4 * 4) = o;
}

// ----------------------------- final: h2(fp32, in d_out) -> bn+relu in-place --
__global__ __launch_bounds__(256) void final_act_kernel(
    const float* __restrict__ h2, const float* __restrict__ scale,
    const float* __restrict__ shift, float* __restrict__ out, int total4)
{
    int i = blockIdx.x * 256 + threadIdx.x;
    if (i >= total4) return;
    int c4 = i & 63;
    float4 v = ((const float4*)h2)[i];
    float4 s = ((const float4*)scale)[c4];
    float4 t = ((const float4*)shift)[c4];
    float4 o;
    o.x = fmaxf(v.x * s.x + t.x, 0.0f);
    o.y = fmaxf(v.y * s.y + t.y, 0.0f);
    o.z = fmaxf(v.z * s.z + t.z, 0.0f);
    o.w = fmaxf(v.w * s.w + t.w, 0.0f);
    ((float4*)out)[i] = o;
}

// ------------------------------------------------------------------ launch --
extern "C" void kernel_launch(void* const* d_in, const int* in_sizes, int n_in,
                              void* d_out, int out_size, void* d_ws, size_t ws_size,
                              hipStream_t stream)
{
    const float* unknown = (const float*)d_in[0];
    const int*   ucnt    = (const int*)d_in[1];
    const float* known   = (const float*)d_in[2];
    const int*   kcnt    = (const int*)d_in[3];
    const float* ufeat   = (const float*)d_in[4];
    const float* kfeat   = (const float*)d_in[5];
    const float* W1      = (const float*)d_in[6];
    const float* g1      = (const float*)d_in[7];
    const float* b1      = (const float*)d_in[8];
    const float* W2      = (const float*)d_in[9];
    const float* g2      = (const float*)d_in[10];
    const float* b2      = (const float*)d_in[11];

    int N = in_sizes[0] / 3;        // 65536
    int B = in_sizes[1];            // 4

    char* ws = (char*)d_ws;
    size_t off = 0;
    float* wgt = (float*)(ws + off);            off += (size_t)N * 3 * 4;
    int*   idxb = (int*)(ws + off);             off += (size_t)N * 3 * 4;
    float* stats = (float*)(ws + off);          off += 8 * 256 * 4;
    float* sum1 = stats,         *sq1 = stats + 256;
    float* scale1 = stats + 512, *shift1 = stats + 768;
    float* sum2 = stats + 1024,  *sq2 = stats + 1280;
    float* scale2 = stats + 1536, *shift2 = stats + 1792;
    unsigned short* W1b = (unsigned short*)(ws + off);  off += 256 * 384 * 2;
    unsigned short* W2b = (unsigned short*)(ws + off);  off += 256 * 256 * 2;
    off = (off + 255) & ~(size_t)255;
    unsigned short* A1 = (unsigned short*)(ws + off);   // N*384 bf16 (50.3MB)
    unsigned short* A2 = A1;                            // aliases A1 (A1 dead by then)
    float* h1 = (float*)d_out;                          // h1, then h2, live in d_out
    float* h2 = (float*)d_out;

    hipMemsetAsync(stats, 0, 8 * 256 * 4, stream);

    knn3_kernel<<<N / 64, 256, 0, stream>>>(unknown, known, ucnt, kcnt,
                                            B, N, wgt, idxb);
    build_a1_kernel<<<N / 4, 256, 0, stream>>>(wgt, idxb, kfeat, ufeat, A1, N);
    wconv_kernel<<<(256 * 384 + 256 * 256 + 255) / 256, 256, 0, stream>>>(
        W1, W2, W1b, W2b, 256 * 384, 256 * 256);
    gemm_bf16_kernel<384><<<dim3(N / 128, 2), 256, 0, stream>>>(A1, W1b, h1);
    bn_stats_kernel<<<512, 256, 0, stream>>>(h1, N, sum1, sq1);
    bn_finalize_kernel<<<1, 256, 0, stream>>>(sum1, sq1, g1, b1, 1.0f / N,
                                              scale1, shift1);
    act1_kernel<<<N / 4, 256, 0, stream>>>(h1, scale1, shift1, A2, N);
    gemm_bf16_kernel<256><<<dim3(N / 128, 2), 256, 0, stream>>>(A2, W2b, h2);
    bn_stats_kernel<<<512, 256, 0, stream>>>(h2, N, sum2, sq2);
    bn_finalize_kernel<<<1, 256, 0, stream>>>(sum2, sq2, g2, b2, 1.0f / N,
                                              scale2, shift2);
    final_act_kernel<<<N / 4, 256, 0, stream>>>(h2, scale2, shift2,
                                                (float*)d_out, N * 64);
}

// Round 4
// 412.681 us; speedup vs baseline: 2.4619x; 1.2971x over previous
//
#include <hip/hip_runtime.h>
#include <math.h>

typedef __attribute__((ext_vector_type(8))) short short8;
typedef __attribute__((ext_vector_type(4))) float f32x4;

#define INF 3.0e38f

__device__ __forceinline__ unsigned short f2bf(float x) {
    union { float f; unsigned u; } v; v.f = x;
    unsigned r = v.u + 0x7FFF + ((v.u >> 16) & 1);   // RNE
    return (unsigned short)(r >> 16);
}

// ---------------------------------------------------------------- 3-NN ----
// Per-thread top-3 via f32 min/med3 network (exact: within a thread the scan
// is ascending-index, so strict-< f32 compares == (d,idx) lex order).
// Cross-thread merge uses exact u64 (f32bits<<32 | idx) lex keys.
// 1024 blocks x 256 thr; block = 64 points, 4 waves scan quarter ranges of
// the LDS-staged knowns (wave-uniform broadcast reads).
__global__ __launch_bounds__(256) void knn3_kernel(
    const float* __restrict__ unk, const float* __restrict__ kn,
    const int* __restrict__ ucnt, const int* __restrict__ kcnt,
    int B, int N, float* __restrict__ wgt, int* __restrict__ idxo)
{
    __shared__ float4 kxyz[1024];
    __shared__ float md[4][64][3];
    __shared__ int   mi[4][64][3];

    int tid = threadIdx.x;
    int s = tid >> 6;
    int lane = tid & 63;
    int pbase = blockIdx.x * 64;
    int p = pbase + lane;

    int cum = 0, bb = 0;
    for (int i = 0; i < B; i++) { int c = ucnt[i]; if (pbase >= cum) bb = i; cum += c; }
    int kstart = 0;
    for (int i = 0; i < bb; i++) kstart += kcnt[i];
    int kend = kstart + kcnt[bb];

    float ux = unk[p * 3 + 0], uy = unk[p * 3 + 1], uz = unk[p * 3 + 2];

    float d0 = INF, d1 = INF, d2 = INF;
    int   i0 = 0, i1 = 0, i2 = 0;

    // 3 f32 cmps + 5 int selects + 5 min/max (nd1 fuses to v_med3_f32)
    auto ins = [&](float e, int gj) {
        bool cA = e < d0;
        bool cB = e < d1;
        bool cC = e < d2;
        int ni0 = cA ? gj : i0;
        int ni1 = cA ? i0 : (cB ? gj : i1);
        int ni2 = cB ? i1 : (cC ? gj : i2);
        float nd0 = fminf(e, d0);
        float nd1 = fminf(fmaxf(e, d0), d1);     // med3(e, d0, d1)
        float nd2 = fminf(d2, fmaxf(e, d1));
        d0 = nd0; d1 = nd1; d2 = nd2;
        i0 = ni0; i1 = ni1; i2 = ni2;
    };

    for (int t0g = kstart; t0g < kend; t0g += 1024) {
        int cnt = min(1024, kend - t0g);
        __syncthreads();
        for (int f = tid; f < cnt * 3; f += 256) {
            int pt = f / 3, c = f - pt * 3;
            ((float*)&kxyz[pt])[c] = kn[(size_t)(t0g + pt) * 3 + c];
        }
        __syncthreads();

        int qlen = cnt >> 2;          // cnt divisible by 4 (4096-per-batch)
        int base = s * qlen;
        for (int i = 0; i < qlen; i += 4) {
            float4 a = kxyz[base + i];
            float4 b4 = kxyz[base + i + 1];
            float4 c4 = kxyz[base + i + 2];
            float4 d4 = kxyz[base + i + 3];
            float ax = ux - a.x,  ay = uy - a.y,  az = uz - a.z;
            float bx = ux - b4.x, by = uy - b4.y, bz = uz - b4.z;
            float cx = ux - c4.x, cy = uy - c4.y, cz = uz - c4.z;
            float dx = ux - d4.x, dy = uy - d4.y, dz = uz - d4.z;
            float e0 = ax * ax + ay * ay + az * az;
            float e1 = bx * bx + by * by + bz * bz;
            float e2 = cx * cx + cy * cy + cz * cz;
            float e3 = dx * dx + dy * dy + dz * dz;
            int gj = t0g + base + i;
            ins(e0, gj + 0);
            ins(e1, gj + 1);
            ins(e2, gj + 2);
            ins(e3, gj + 3);
        }
    }

    md[s][lane][0] = d0; md[s][lane][1] = d1; md[s][lane][2] = d2;
    mi[s][lane][0] = i0; mi[s][lane][1] = i1; mi[s][lane][2] = i2;
    __syncthreads();

    if (tid < 64) {
        unsigned long long s0 = ~0ULL, s1 = ~0ULL, s2 = ~0ULL;
        auto insK = [&](unsigned long long k) {
            bool c0 = k < s0;
            unsigned long long t0 = c0 ? k : s0;
            unsigned long long t1 = c0 ? s0 : k;
            bool c1 = t1 < s1;
            unsigned long long u0 = c1 ? t1 : s1;
            unsigned long long u1 = c1 ? s1 : t1;
            s0 = t0; s1 = u0;
            s2 = u1 < s2 ? u1 : s2;
        };
#pragma unroll
        for (int qq = 0; qq < 4; qq++)
#pragma unroll
            for (int kk = 0; kk < 3; kk++)
                insK(((unsigned long long)__float_as_uint(md[qq][tid][kk]) << 32)
                     | (unsigned)mi[qq][tid][kk]);

        float dd0 = __uint_as_float((unsigned)(s0 >> 32));
        float dd1 = __uint_as_float((unsigned)(s1 >> 32));
        float dd2 = __uint_as_float((unsigned)(s2 >> 32));
        float r0 = 1.0f / (dd0 + 1e-8f);
        float r1 = 1.0f / (dd1 + 1e-8f);
        float r2 = 1.0f / (dd2 + 1e-8f);
        float rs = 1.0f / (r0 + r1 + r2);
        int pp = pbase + tid;
        wgt[pp * 3 + 0] = r0 * rs;
        wgt[pp * 3 + 1] = r1 * rs;
        wgt[pp * 3 + 2] = r2 * rs;
        idxo[pp * 3 + 0] = (int)(unsigned)s0;
        idxo[pp * 3 + 1] = (int)(unsigned)s1;
        idxo[pp * 3 + 2] = (int)(unsigned)s2;
    }
}

// --------------------------- build A1 = [interp | ufeat] as bf16 [N,384] --
__global__ __launch_bounds__(256) void build_a1_kernel(
    const float* __restrict__ wgt, const int* __restrict__ idxv,
    const float* __restrict__ kfeat, const float* __restrict__ ufeat,
    unsigned short* __restrict__ A1, int N)
{
    int t = blockIdx.x * 256 + threadIdx.x;
    int p = t >> 6, c4 = t & 63;
    if (p >= N) return;
    float w0 = wgt[p * 3 + 0], w1 = wgt[p * 3 + 1], w2 = wgt[p * 3 + 2];
    int j0 = idxv[p * 3 + 0], j1 = idxv[p * 3 + 1], j2 = idxv[p * 3 + 2];
    float4 v0 = ((const float4*)(kfeat + (size_t)j0 * 256))[c4];
    float4 v1 = ((const float4*)(kfeat + (size_t)j1 * 256))[c4];
    float4 v2 = ((const float4*)(kfeat + (size_t)j2 * 256))[c4];
    ushort4 ob;
    ob.x = f2bf(v0.x * w0 + v1.x * w1 + v2.x * w2);
    ob.y = f2bf(v0.y * w0 + v1.y * w1 + v2.y * w2);
    ob.z = f2bf(v0.z * w0 + v1.z * w1 + v2.z * w2);
    ob.w = f2bf(v0.w * w0 + v1.w * w1 + v2.w * w2);
    *(ushort4*)(A1 + (size_t)p * 384 + c4 * 4) = ob;
    float2 u = ((const float2*)(ufeat + (size_t)p * 128))[c4];
    ushort2 ub; ub.x = f2bf(u.x); ub.y = f2bf(u.y);
    *(ushort2*)(A1 + (size_t)p * 384 + 256 + c4 * 2) = ub;
}

// ------------------------------------------------ weight fp32->bf16 conv --
__global__ __launch_bounds__(256) void wconv_kernel(
    const float* __restrict__ W1, const float* __restrict__ W2,
    unsigned short* __restrict__ W1b, unsigned short* __restrict__ W2b,
    int n1, int n2)
{
    int i = blockIdx.x * 256 + threadIdx.x;
    if (i < n1) W1b[i] = f2bf(W1[i]);
    int j = i - n1;
    if (j >= 0 && j < n2) W2b[j] = f2bf(W2[j]);
}

// -------------------------------------------------------- bf16 MFMA GEMM --
// C[N,256] = A[N,K] x W[256,K]^T.  128x128 tile, BK=32, 16x16x32 MFMA.
// MODE 0: A is bf16 [N,K].
// MODE 1: A is fp32 [N,K]; staging applies relu(A*scale+shift) then bf16.
// Fused epilogue: per-block column sum/sumsq of C -> global atomics (BN stats).
template <int K, int MODE>
__global__ __launch_bounds__(256) void gemm_bf16_kernel(
    const void* __restrict__ Av, const unsigned short* __restrict__ W,
    const float* __restrict__ scale, const float* __restrict__ shift,
    float* __restrict__ C, float* __restrict__ gsum, float* __restrict__ gsq)
{
    __shared__ unsigned short As[128 * 40];
    __shared__ unsigned short Bs[128 * 40];
    __shared__ float colsum[128];
    __shared__ float colsq[128];

    int tid = threadIdx.x;
    int w = tid >> 6, lane = tid & 63;
    int r = w >> 1, cq = w & 1;
    int m16 = lane & 15, q = lane >> 4;
    int bm = blockIdx.x * 128, bn = blockIdx.y * 128;

    f32x4 acc[4][4];
#pragma unroll
    for (int i = 0; i < 4; i++)
#pragma unroll
        for (int j = 0; j < 4; j++) acc[i][j] = (f32x4){0.f, 0.f, 0.f, 0.f};

#pragma unroll
    for (int k0 = 0; k0 < K; k0 += 32) {
        __syncthreads();
#pragma unroll
        for (int i = 0; i < 2; i++) {
            int id = tid + i * 256;
            int row = id >> 2, kc = (id & 3) * 8;
            if (MODE == 0) {
                *(short8*)&As[row * 40 + kc] =
                    *(const short8*)((const unsigned short*)Av +
                                     (size_t)(bm + row) * K + k0 + kc);
            } else {
                const float* Af = (const float*)Av;
                float4 v0 = *(const float4*)(Af + (size_t)(bm + row) * K + k0 + kc);
                float4 v1 = *(const float4*)(Af + (size_t)(bm + row) * K + k0 + kc + 4);
                float4 s0 = *(const float4*)(scale + k0 + kc);
                float4 s1 = *(const float4*)(scale + k0 + kc + 4);
                float4 t0 = *(const float4*)(shift + k0 + kc);
                float4 t1 = *(const float4*)(shift + k0 + kc + 4);
                ushort4 o0, o1;
                o0.x = f2bf(fmaxf(v0.x * s0.x + t0.x, 0.f));
                o0.y = f2bf(fmaxf(v0.y * s0.y + t0.y, 0.f));
                o0.z = f2bf(fmaxf(v0.z * s0.z + t0.z, 0.f));
                o0.w = f2bf(fmaxf(v0.w * s0.w + t0.w, 0.f));
                o1.x = f2bf(fmaxf(v1.x * s1.x + t1.x, 0.f));
                o1.y = f2bf(fmaxf(v1.y * s1.y + t1.y, 0.f));
                o1.z = f2bf(fmaxf(v1.z * s1.z + t1.z, 0.f));
                o1.w = f2bf(fmaxf(v1.w * s1.w + t1.w, 0.f));
                *(ushort4*)&As[row * 40 + kc] = o0;
                *(ushort4*)&As[row * 40 + kc + 4] = o1;
            }
            *(short8*)&Bs[row * 40 + kc] =
                *(const short8*)(W + (size_t)(bn + row) * K + k0 + kc);
        }
        __syncthreads();

        short8 af[4], bf[4];
#pragma unroll
        for (int sub = 0; sub < 4; sub++) {
            af[sub] = *(const short8*)&As[(r * 64 + sub * 16 + m16) * 40 + q * 8];
            bf[sub] = *(const short8*)&Bs[(cq * 64 + sub * 16 + m16) * 40 + q * 8];
        }
#pragma unroll
        for (int sm = 0; sm < 4; sm++)
#pragma unroll
            for (int sn = 0; sn < 4; sn++)
                acc[sm][sn] = __builtin_amdgcn_mfma_f32_16x16x32_bf16(
                    af[sm], bf[sn], acc[sm][sn], 0, 0, 0);
    }

    int row0 = bm + r * 64 + q * 4;
    int col0 = bn + cq * 64 + m16;
#pragma unroll
    for (int sm = 0; sm < 4; sm++)
#pragma unroll
        for (int sn = 0; sn < 4; sn++) {
            f32x4 v = acc[sm][sn];
#pragma unroll
            for (int reg = 0; reg < 4; reg++)
                C[(size_t)(row0 + sm * 16 + reg) * 256 + col0 + sn * 16] = v[reg];
        }

    // ---- fused BN stats: per-block column sums of the 128x128 C tile ----
    __syncthreads();
    if (tid < 128) { colsum[tid] = 0.f; colsq[tid] = 0.f; }
    __syncthreads();
#pragma unroll
    for (int sn = 0; sn < 4; sn++) {
        float sacc = 0.f, qacc = 0.f;
#pragma unroll
        for (int sm = 0; sm < 4; sm++) {
            f32x4 v = acc[sm][sn];
#pragma unroll
            for (int reg = 0; reg < 4; reg++) {
                sacc += v[reg];
                qacc += v[reg] * v[reg];
            }
        }
        int lc = cq * 64 + sn * 16 + m16;
        atomicAdd(&colsum[lc], sacc);
        atomicAdd(&colsq[lc], qacc);
    }
    __syncthreads();
    if (tid < 128) {
        atomicAdd(&gsum[bn + tid], colsum[tid]);
        atomicAdd(&gsq[bn + tid], colsq[tid]);
    }
}

__global__ void bn_finalize_kernel(
    const float* __restrict__ sum, const float* __restrict__ sumsq,
    const float* __restrict__ g, const float* __restrict__ bta, float invN,
    float* __restrict__ scale, float* __restrict__ shift)
{
    int c = threadIdx.x;
    float mean = sum[c] * invN;
    float var = sumsq[c] * invN - mean * mean;   // biased, matches torch BN
    float sc = g[c] * rsqrtf(var + 1e-5f);
    scale[c] = sc;
    shift[c] = bta[c] - mean * sc;
}

// ----------------------------- final: h2(ws) -> bn+relu -> d_out ----------
__global__ __launch_bounds__(256) void final_act_kernel(
    const float* __restrict__ h2, const float* __restrict__ scale,
    const float* __restrict__ shift, float* __restrict__ out, int total4)
{
    int i = blockIdx.x * 256 + threadIdx.x;
    if (i >= total4) return;
    int c4 = i & 63;
    float4 v = ((const float4*)h2)[i];
    float4 s = ((const float4*)scale)[c4];
    float4 t = ((const float4*)shift)[c4];
    float4 o;
    o.x = fmaxf(v.x * s.x + t.x, 0.0f);
    o.y = fmaxf(v.y * s.y + t.y, 0.0f);
    o.z = fmaxf(v.z * s.z + t.z, 0.0f);
    o.w = fmaxf(v.w * s.w + t.w, 0.0f);
    ((float4*)out)[i] = o;
}

// ------------------------------------------------------------------ launch --
extern "C" void kernel_launch(void* const* d_in, const int* in_sizes, int n_in,
                              void* d_out, int out_size, void* d_ws, size_t ws_size,
                              hipStream_t stream)
{
    const float* unknown = (const float*)d_in[0];
    const int*   ucnt    = (const int*)d_in[1];
    const float* known   = (const float*)d_in[2];
    const int*   kcnt    = (const int*)d_in[3];
    const float* ufeat   = (const float*)d_in[4];
    const float* kfeat   = (const float*)d_in[5];
    const float* W1      = (const float*)d_in[6];
    const float* g1      = (const float*)d_in[7];
    const float* b1      = (const float*)d_in[8];
    const float* W2      = (const float*)d_in[9];
    const float* g2      = (const float*)d_in[10];
    const float* b2      = (const float*)d_in[11];

    int N = in_sizes[0] / 3;        // 65536
    int B = in_sizes[1];            // 4

    char* ws = (char*)d_ws;
    size_t off = 0;
    float* wgt = (float*)(ws + off);            off += (size_t)N * 3 * 4;
    int*   idxb = (int*)(ws + off);             off += (size_t)N * 3 * 4;
    float* stats = (float*)(ws + off);          off += 8 * 256 * 4;
    float* sum1 = stats,         *sq1 = stats + 256;
    float* scale1 = stats + 512, *shift1 = stats + 768;
    float* sum2 = stats + 1024,  *sq2 = stats + 1280;
    float* scale2 = stats + 1536, *shift2 = stats + 1792;
    unsigned short* W1b = (unsigned short*)(ws + off);  off += 256 * 384 * 2;
    unsigned short* W2b = (unsigned short*)(ws + off);  off += 256 * 256 * 2;
    off = (off + 255) & ~(size_t)255;
    // big region: A1 (bf16 N*384 = 50.3MB) for gemm1, then reused as
    // h2 (fp32 N*256 = 67MB) for gemm2 output. Peak ws ~69MB (proven r2 size).
    unsigned short* A1 = (unsigned short*)(ws + off);
    float* h2 = (float*)(ws + off);
    float* h1 = (float*)d_out;                  // h1 lives in d_out

    hipMemsetAsync(stats, 0, 8 * 256 * 4, stream);

    knn3_kernel<<<N / 64, 256, 0, stream>>>(unknown, known, ucnt, kcnt,
                                            B, N, wgt, idxb);
    build_a1_kernel<<<N / 4, 256, 0, stream>>>(wgt, idxb, kfeat, ufeat, A1, N);
    wconv_kernel<<<(256 * 384 + 256 * 256 + 255) / 256, 256, 0, stream>>>(
        W1, W2, W1b, W2b, 256 * 384, 256 * 256);
    gemm_bf16_kernel<384, 0><<<dim3(N / 128, 2), 256, 0, stream>>>(
        A1, W1b, nullptr, nullptr, h1, sum1, sq1);
    bn_finalize_kernel<<<1, 256, 0, stream>>>(sum1, sq1, g1, b1, 1.0f / N,
                                              scale1, shift1);
    gemm_bf16_kernel<256, 1><<<dim3(N / 128, 2), 256, 0, stream>>>(
        h1, W2b, scale1, shift1, h2, sum2, sq2);
    bn_finalize_kernel<<<1, 256, 0, stream>>>(sum2, sq2, g2, b2, 1.0f / N,
                                              scale2, shift2);
    final_act_kernel<<<N / 4, 256, 0, stream>>>(h2, scale2, shift2,
                                                (float*)d_out, N * 64);
}